// Round 1
// baseline (6585.757 us; speedup 1.0000x reference)
//
#include <hip/hip_runtime.h>
#include <stdint.h>

#define B_  64
#define T_  512
#define I_  512
#define H_  1024
#define G4  4096
#define KW  1536   // rows of W_t = I_ + H_

#define GROUPS 2
#define GBLK   64    // blocks per group
#define MB     32    // batch rows per group

typedef __attribute__((ext_vector_type(8))) short bf16x8;
typedef __attribute__((ext_vector_type(4))) float f32x4;

// ---- ws layout (bytes) ----
#define OFF_WT   ((size_t)0)                        // 4096*1536*2 = 12,582,912
#define OFF_XU   ((size_t)(16u << 20))              // 512*4096*64*2 = 268,435,456
#define OFF_HB   (OFF_XU + (size_t)268435456)       // 2*64*1024*2 = 262,144
#define OFF_CTR  (OFF_HB + (size_t)262144)
#define WS_NEED  (OFF_CTR + (size_t)256)

__device__ __forceinline__ unsigned short f2bf(float x) {
  unsigned u = __float_as_uint(x);
  u += 0x7FFFu + ((u >> 16) & 1u);        // RNE
  return (unsigned short)(u >> 16);
}
__device__ __forceinline__ float sigm(float x) {
  return 1.0f / (1.0f + __expf(-x));
}

// ============ kernel 0: pack [U;V] -> W_t[col][k] bf16 (transposed) ============
__global__ __launch_bounds__(256) void pack_w_kernel(
    const float* __restrict__ U0, const float* __restrict__ U1,
    const float* __restrict__ U2, const float* __restrict__ U3,
    const float* __restrict__ V0, const float* __restrict__ V1,
    const float* __restrict__ V2, const float* __restrict__ V3,
    short* __restrict__ Wt)
{
  __shared__ short sl[64][65];
  const int c0 = blockIdx.x * 64;         // col tile (within one gate: 64 | 1024)
  const int k0 = blockIdx.y * 64;         // k tile (within U or V: 64 | 512)
  const int g  = c0 >> 10;
  const int h0 = c0 & 1023;
  const float* srcU = (g == 0 ? U0 : g == 1 ? U1 : g == 2 ? U2 : U3);
  const float* srcV = (g == 0 ? V0 : g == 1 ? V1 : g == 2 ? V2 : V3);
  const float* src  = (k0 < 512) ? (srcU + (size_t)k0 * H_)
                                 : (srcV + (size_t)(k0 - 512) * H_);
  const int tid = threadIdx.x;
  const int cl = tid & 63;
  const int r4 = tid >> 6;
  #pragma unroll
  for (int r = 0; r < 16; ++r) {
    const int kl = r * 4 + r4;
    sl[kl][cl] = (short)f2bf(src[(size_t)kl * H_ + h0 + cl]);
  }
  __syncthreads();
  #pragma unroll
  for (int r = 0; r < 16; ++r) {
    const int cl2 = r * 4 + r4;
    Wt[(size_t)(c0 + cl2) * KW + k0 + cl] = sl[cl][cl2];
  }
}

// ============ kernel 1: xu[t][gc][b] = bf16( x_t @ U + bias ) ============
__global__ __launch_bounds__(512) void xu_gemm(
    const float* __restrict__ x,
    const float* __restrict__ b0g, const float* __restrict__ b1g,
    const float* __restrict__ b2g, const float* __restrict__ b3g,
    const short* __restrict__ Wt, short* __restrict__ xu)
{
  __shared__ short sa[64 * 512];          // A tile (64 b-rows x 512 k) bf16, swizzled
  const int t  = blockIdx.y;
  const int cb = blockIdx.x * 256;        // col base (within one gate: 256 | 1024)
  const int tid = threadIdx.x;

  { // stage x[b][t][:] -> sa (fp32 -> bf16)
    const int b  = tid >> 3;
    const int kc = (tid & 7) * 64;
    const float* xp = x + ((size_t)b * T_ + t) * I_ + kc;
    const int xr = (b & 7) << 3;
    #pragma unroll
    for (int i = 0; i < 16; ++i) {
      const float4 v = *(const float4*)(xp + i * 4);
      const int k = kc + i * 4;
      uint2 pk;
      pk.x = (unsigned)f2bf(v.x) | ((unsigned)f2bf(v.y) << 16);
      pk.y = (unsigned)f2bf(v.z) | ((unsigned)f2bf(v.w) << 16);
      *(uint2*)(sa + b * 512 + (k ^ xr)) = pk;
    }
  }
  __syncthreads();

  const int w = tid >> 6, l = tid & 63;
  const int m  = w & 3;                   // 4 m-tiles (batch)
  const int nh = w >> 2;                  // 2 halves of 16 n-tiles
  const int cit = l & 15;
  const int klane = (l >> 4) * 8;
  const int arow = m * 16 + cit;
  const int xrr = (arow & 7) << 3;
  const int bm = m * 16 + ((l >> 4) << 2);

  const int gate = cb >> 10;
  const float* bias = (gate == 0 ? b0g : gate == 1 ? b1g : gate == 2 ? b2g : b3g);

  f32x4 acc[8];
  #pragma unroll
  for (int n = 0; n < 8; ++n) {
    const int gc = cb + (nh * 8 + n) * 16 + cit;
    const float bv = bias[gc & 1023];
    acc[n] = (f32x4){bv, bv, bv, bv};
  }

  for (int kk = 0; kk < 16; ++kk) {
    const int k = kk * 32 + klane;
    const bf16x8 af = *(const bf16x8*)(sa + arow * 512 + (k ^ xrr));
    #pragma unroll
    for (int n = 0; n < 8; ++n) {
      const int gc = cb + (nh * 8 + n) * 16 + cit;
      const bf16x8 bf = *(const bf16x8*)(Wt + (size_t)gc * KW + k);
      acc[n] = __builtin_amdgcn_mfma_f32_16x16x32_bf16(af, bf, acc[n], 0, 0, 0);
    }
  }

  #pragma unroll
  for (int n = 0; n < 8; ++n) {
    const int gc = cb + (nh * 8 + n) * 16 + cit;
    uint2 pk;
    pk.x = (unsigned)f2bf(acc[n][0]) | ((unsigned)f2bf(acc[n][1]) << 16);
    pk.y = (unsigned)f2bf(acc[n][2]) | ((unsigned)f2bf(acc[n][3]) << 16);
    *(uint2*)(xu + ((size_t)t * G4 + gc) * 64 + bm) = pk;
  }
}

// ============ kernel 2: persistent recurrence ============
__global__ __launch_bounds__(512, 1) void lstm_rec(
    const short* __restrict__ Wt, const short* __restrict__ xu,
    short* __restrict__ hb, unsigned* __restrict__ ctr, float* __restrict__ out)
{
  __shared__ short sh[MB * 1024];          // 64 KiB h-tile; gates overlay below
  float* gl = (float*)sh;                  // [MB][68] f32 overlay

  const int tid = threadIdx.x;
  const int blk = blockIdx.x;
  const int g   = blk >> 6;                // group (batch half)
  const int bi  = blk & 63;
  const int base = bi * 16;                // 16 h-cols per block
  const int b0  = g * MB;

  const int w = tid >> 6, l = tid & 63;
  const int m = w & 1;                     // 2 m-tiles of 16 rows
  const int n = w >> 1;                    // gate 0..3
  const int cit = l & 15;
  const int klane = (l >> 4) * 8;
  const int arow = m * 16 + cit;
  const int xr_a = (arow & 7) << 3;
  const int gc = n * 1024 + base + cit;
  const short* wp = Wt + (size_t)gc * KW + 512 + klane;
  const int bm = m * 16 + ((l >> 4) << 2);

  const int cj = tid & 15;
  const int bl = tid >> 4;                 // 0..31 local batch row (combine)
  unsigned* ctr_g = ctr + g * 16;

  float c_state = 0.0f;

  for (int t = 0; t < T_; ++t) {
    // prefetch xu for this step (completes under the coherent staging)
    const uint2 pxu = *(const uint2*)(xu + ((size_t)t * G4 + gc) * 64 + b0 + bm);

    { // ---- stage h (device-coherent, bypass L2) into LDS, swizzled ----
      const short* hsrc = hb + (size_t)(t & 1) * (B_ * H_) + (size_t)b0 * H_;
      int4 v0, v1, v2, v3, v4, v5, v6, v7;
      const short* p;
      #define LDC(ii, vv) \
        p = hsrc + (size_t)((ii) * 512 + tid) * 8; \
        asm volatile("global_load_dwordx4 %0, %1, off sc0 sc1" : "=&v"(vv) : "v"(p));
      LDC(0, v0) LDC(1, v1) LDC(2, v2) LDC(3, v3)
      LDC(4, v4) LDC(5, v5) LDC(6, v6) LDC(7, v7)
      #undef LDC
      asm volatile("s_waitcnt vmcnt(0)" ::: "memory");
      __builtin_amdgcn_sched_barrier(0);
      #define STC(ii, vv) { const int f = (ii) * 512 + tid; const int row = f >> 7; \
        const int k0 = (f & 127) * 8; \
        *(int4*)(sh + row * 1024 + (k0 ^ ((row & 7) << 3))) = vv; }
      STC(0, v0) STC(1, v1) STC(2, v2) STC(3, v3)
      STC(4, v4) STC(5, v5) STC(6, v6) STC(7, v7)
      #undef STC
    }
    __syncthreads();

    // ---- acc init from xu (bias already folded) ----
    f32x4 acc;
    acc[0] = __uint_as_float(pxu.x << 16);
    acc[1] = __uint_as_float(pxu.x & 0xffff0000u);
    acc[2] = __uint_as_float(pxu.y << 16);
    acc[3] = __uint_as_float(pxu.y & 0xffff0000u);

    // ---- gates += h @ V  (K = 1024) ----
    #pragma unroll 1
    for (int kk0 = 0; kk0 < 32; kk0 += 8) {
      bf16x8 bfr[8];
      #pragma unroll
      for (int j = 0; j < 8; ++j)
        bfr[j] = *(const bf16x8*)(wp + (size_t)(kk0 + j) * 32);
      #pragma unroll
      for (int j = 0; j < 8; ++j) {
        const int k = (kk0 + j) * 32 + klane;
        const bf16x8 af = *(const bf16x8*)(sh + arow * 1024 + (k ^ xr_a));
        acc = __builtin_amdgcn_mfma_f32_16x16x32_bf16(af, bfr[j], acc, 0, 0, 0);
      }
    }
    __syncthreads();   // all LDS h reads done -> overlay is safe

    #pragma unroll
    for (int i = 0; i < 4; ++i)
      gl[(bm + i) * 68 + n * 16 + cit] = acc[i];
    __syncthreads();

    { // ---- combine: per-thread one (b, j) ----
      const float gi = gl[bl * 68 +  0 + cj];
      const float gf = gl[bl * 68 + 16 + cj];
      const float gg = gl[bl * 68 + 32 + cj];
      const float go = gl[bl * 68 + 48 + cj];
      const float i_ = sigm(gi), f_ = sigm(gf), g_ = sigm(gg), o_ = sigm(go);
      c_state = f_ * c_state + i_ * g_;
      const float h = o_ * tanhf(c_state);
      const int b = b0 + bl;
      out[((size_t)b << 19) + (size_t)t * H_ + base + cj] = h;
      const unsigned hv = (unsigned)f2bf(h);
      short* hdst = hb + (size_t)((t + 1) & 1) * (B_ * H_) + (size_t)b * H_ + base + cj;
      asm volatile("global_store_short %0, %1, off sc0 sc1" :: "v"(hdst), "v"(hv) : "memory");
      if (t == T_ - 1) {
        out[(size_t)B_ * T_ * H_ + (size_t)b * H_ + base + cj] = h;
        out[(size_t)B_ * T_ * H_ + (size_t)B_ * H_ + (size_t)b * H_ + base + cj] = c_state;
      }
    }
    asm volatile("s_waitcnt vmcnt(0)" ::: "memory");
    __syncthreads();
    if (tid == 0) {
      atomicAdd(ctr_g, 1u);
      if (t + 1 < T_) {
        const unsigned target = (unsigned)GBLK * (unsigned)(t + 1);
        while (__hip_atomic_load(ctr_g, __ATOMIC_RELAXED, __HIP_MEMORY_SCOPE_AGENT) < target)
          __builtin_amdgcn_s_sleep(1);
      }
    }
    __syncthreads();
  }
}

extern "C" void kernel_launch(void* const* d_in, const int* in_sizes, int n_in,
                              void* d_out, int out_size, void* d_ws, size_t ws_size,
                              hipStream_t stream)
{
  const float* x  = (const float*)d_in[0];
  const float* U0 = (const float*)d_in[1];
  const float* Vg0 = (const float*)d_in[2];
  const float* bg0 = (const float*)d_in[3];
  const float* U1 = (const float*)d_in[4];
  const float* Vg1 = (const float*)d_in[5];
  const float* bg1 = (const float*)d_in[6];
  const float* U2 = (const float*)d_in[7];
  const float* Vg2 = (const float*)d_in[8];
  const float* bg2 = (const float*)d_in[9];
  const float* U3 = (const float*)d_in[10];
  const float* Vg3 = (const float*)d_in[11];
  const float* bg3 = (const float*)d_in[12];

  if (ws_size < WS_NEED) return;  // diagnostic: leaves d_out poisoned

  char* ws = (char*)d_ws;
  short* Wt = (short*)(ws + OFF_WT);
  short* xu = (short*)(ws + OFF_XU);
  short* hb = (short*)(ws + OFF_HB);
  unsigned* ctr = (unsigned*)(ws + OFF_CTR);

  hipMemsetAsync(ws + OFF_HB, 0, (size_t)(2 * B_ * H_ * 2) + 256, stream);
  pack_w_kernel<<<dim3(64, 24), 256, 0, stream>>>(U0, U1, U2, U3, Vg0, Vg1, Vg2, Vg3, Wt);
  xu_gemm<<<dim3(16, 512), 512, 0, stream>>>(x, bg0, bg1, bg2, bg3, Wt, xu);
  lstm_rec<<<dim3(GROUPS * GBLK), 512, 0, stream>>>(Wt, xu, hb, ctr, (float*)d_out);
}

// Round 2
// 6374.155 us; speedup vs baseline: 1.0332x; 1.0332x over previous
//
#include <hip/hip_runtime.h>
#include <stdint.h>

#define B_  64
#define T_  512
#define I_  512
#define H_  1024
#define G4  4096
#define KW  1536   // rows of W_t = I_ + H_

#define GROUPS 2
#define GBLK   64    // blocks per group
#define MB     32    // batch rows per group

typedef __attribute__((ext_vector_type(8))) short bf16x8;
typedef __attribute__((ext_vector_type(4))) float f32x4;

// ---- ws layout (bytes) ----
#define OFF_WT   ((size_t)0)                        // 4096*1536*2 = 12,582,912
#define OFF_XU   ((size_t)(16u << 20))              // 512*4096*64*2 = 268,435,456
#define OFF_HB   (OFF_XU + (size_t)268435456)       // 2*64*1024*2 = 262,144
#define OFF_FLG  (OFF_HB + (size_t)262144)          // 2 groups * 64 flags * 64B = 8192
#define WS_NEED  (OFF_FLG + (size_t)8192)

__device__ __forceinline__ unsigned short f2bf(float x) {
  unsigned u = __float_as_uint(x);
  u += 0x7FFFu + ((u >> 16) & 1u);        // RNE
  return (unsigned short)(u >> 16);
}
__device__ __forceinline__ float sigm(float x) {
  return 1.0f / (1.0f + __expf(-x));
}

// ============ kernel 0: pack [U;V] -> W_t[col][k] bf16 (transposed) ============
__global__ __launch_bounds__(256) void pack_w_kernel(
    const float* __restrict__ U0, const float* __restrict__ U1,
    const float* __restrict__ U2, const float* __restrict__ U3,
    const float* __restrict__ V0, const float* __restrict__ V1,
    const float* __restrict__ V2, const float* __restrict__ V3,
    short* __restrict__ Wt)
{
  __shared__ short sl[64][65];
  const int c0 = blockIdx.x * 64;         // col tile (within one gate: 64 | 1024)
  const int k0 = blockIdx.y * 64;         // k tile (within U or V: 64 | 512)
  const int g  = c0 >> 10;
  const int h0 = c0 & 1023;
  const float* srcU = (g == 0 ? U0 : g == 1 ? U1 : g == 2 ? U2 : U3);
  const float* srcV = (g == 0 ? V0 : g == 1 ? V1 : g == 2 ? V2 : V3);
  const float* src  = (k0 < 512) ? (srcU + (size_t)k0 * H_)
                                 : (srcV + (size_t)(k0 - 512) * H_);
  const int tid = threadIdx.x;
  const int cl = tid & 63;
  const int r4 = tid >> 6;
  #pragma unroll
  for (int r = 0; r < 16; ++r) {
    const int kl = r * 4 + r4;
    sl[kl][cl] = (short)f2bf(src[(size_t)kl * H_ + h0 + cl]);
  }
  __syncthreads();
  #pragma unroll
  for (int r = 0; r < 16; ++r) {
    const int cl2 = r * 4 + r4;
    Wt[(size_t)(c0 + cl2) * KW + k0 + cl] = sl[cl][cl2];
  }
}

// ============ kernel 1: xu[t][gc][b] = bf16( x_t @ U + bias ) ============
__global__ __launch_bounds__(512) void xu_gemm(
    const float* __restrict__ x,
    const float* __restrict__ b0g, const float* __restrict__ b1g,
    const float* __restrict__ b2g, const float* __restrict__ b3g,
    const short* __restrict__ Wt, short* __restrict__ xu)
{
  __shared__ short sa[64 * 512];          // A tile (64 b-rows x 512 k) bf16, swizzled
  const int t  = blockIdx.y;
  const int cb = blockIdx.x * 256;        // col base (within one gate: 256 | 1024)
  const int tid = threadIdx.x;

  { // stage x[b][t][:] -> sa (fp32 -> bf16)
    const int b  = tid >> 3;
    const int kc = (tid & 7) * 64;
    const float* xp = x + ((size_t)b * T_ + t) * I_ + kc;
    const int xr = (b & 7) << 3;
    #pragma unroll
    for (int i = 0; i < 16; ++i) {
      const float4 v = *(const float4*)(xp + i * 4);
      const int k = kc + i * 4;
      uint2 pk;
      pk.x = (unsigned)f2bf(v.x) | ((unsigned)f2bf(v.y) << 16);
      pk.y = (unsigned)f2bf(v.z) | ((unsigned)f2bf(v.w) << 16);
      *(uint2*)(sa + b * 512 + (k ^ xr)) = pk;
    }
  }
  __syncthreads();

  const int w = tid >> 6, l = tid & 63;
  const int m  = w & 3;                   // 4 m-tiles (batch)
  const int nh = w >> 2;                  // 2 halves of 16 n-tiles
  const int cit = l & 15;
  const int klane = (l >> 4) * 8;
  const int arow = m * 16 + cit;
  const int xrr = (arow & 7) << 3;
  const int bm = m * 16 + ((l >> 4) << 2);

  const int gate = cb >> 10;
  const float* bias = (gate == 0 ? b0g : gate == 1 ? b1g : gate == 2 ? b2g : b3g);

  f32x4 acc[8];
  #pragma unroll
  for (int n = 0; n < 8; ++n) {
    const int gc = cb + (nh * 8 + n) * 16 + cit;
    const float bv = bias[gc & 1023];
    acc[n] = (f32x4){bv, bv, bv, bv};
  }

  for (int kk = 0; kk < 16; ++kk) {
    const int k = kk * 32 + klane;
    const bf16x8 af = *(const bf16x8*)(sa + arow * 512 + (k ^ xrr));
    #pragma unroll
    for (int n = 0; n < 8; ++n) {
      const int gc = cb + (nh * 8 + n) * 16 + cit;
      const bf16x8 bf = *(const bf16x8*)(Wt + (size_t)gc * KW + k);
      acc[n] = __builtin_amdgcn_mfma_f32_16x16x32_bf16(af, bf, acc[n], 0, 0, 0);
    }
  }

  #pragma unroll
  for (int n = 0; n < 8; ++n) {
    const int gc = cb + (nh * 8 + n) * 16 + cit;
    uint2 pk;
    pk.x = (unsigned)f2bf(acc[n][0]) | ((unsigned)f2bf(acc[n][1]) << 16);
    pk.y = (unsigned)f2bf(acc[n][2]) | ((unsigned)f2bf(acc[n][3]) << 16);
    *(uint2*)(xu + ((size_t)t * G4 + gc) * 64 + bm) = pk;
  }
}

// ============ kernel 2: persistent recurrence ============
__global__ __launch_bounds__(512, 1) void lstm_rec(
    const short* __restrict__ Wt, const short* __restrict__ xu,
    short* __restrict__ hb, unsigned* __restrict__ flg, float* __restrict__ out)
{
  __shared__ short sh[MB * 1024];          // 64 KiB h-tile; gates overlay below
  float* gl = (float*)sh;                  // [MB][68] f32 overlay

  const int tid = threadIdx.x;
  const int blk = blockIdx.x;
  const int g   = blk >> 6;                // group (batch half)
  const int bi  = blk & 63;
  const int base = bi * 16;                // 16 h-cols per block
  const int b0  = g * MB;

  const int w = tid >> 6, l = tid & 63;
  const int m = w & 1;                     // 2 m-tiles of 16 rows
  const int n = w >> 1;                    // gate 0..3
  const int cit = l & 15;
  const int klane = (l >> 4) * 8;
  const int arow = m * 16 + cit;
  const int xr_a = (arow & 7) << 3;
  const int gc = n * 1024 + base + cit;
  const short* wp = Wt + (size_t)gc * KW + 512 + klane;
  const int bm = m * 16 + ((l >> 4) << 2);

  const int cj = tid & 15;
  const int bl = tid >> 4;                 // 0..31 local batch row (combine)

  // flag lines: group g at flg + g*1024 dwords; block bi's flag at + bi*16 dwords (64B apart)
  unsigned* myflag = flg + (size_t)g * 1024 + (size_t)bi * 16;
  unsigned* pollp  = flg + (size_t)g * 1024 + (size_t)(tid & 63) * 16;

  float c_state = 0.0f;

  for (int t = 0; t < T_; ++t) {
    // prefetch xu for this step (completes under the coherent staging)
    const uint2 pxu = *(const uint2*)(xu + ((size_t)t * G4 + gc) * 64 + b0 + bm);

    { // ---- stage h (device-coherent, bypass L2) into LDS, swizzled ----
      const short* hsrc = hb + (size_t)(t & 1) * (B_ * H_) + (size_t)b0 * H_;
      int4 v0, v1, v2, v3, v4, v5, v6, v7;
      const short* p;
      #define LDC(ii, vv) \
        p = hsrc + (size_t)((ii) * 512 + tid) * 8; \
        asm volatile("global_load_dwordx4 %0, %1, off sc0 sc1" : "=&v"(vv) : "v"(p));
      LDC(0, v0) LDC(1, v1) LDC(2, v2) LDC(3, v3)
      LDC(4, v4) LDC(5, v5) LDC(6, v6) LDC(7, v7)
      #undef LDC
      asm volatile("s_waitcnt vmcnt(0)" ::: "memory");
      __builtin_amdgcn_sched_barrier(0);
      #define STC(ii, vv) { const int f = (ii) * 512 + tid; const int row = f >> 7; \
        const int k0 = (f & 127) * 8; \
        *(int4*)(sh + row * 1024 + (k0 ^ ((row & 7) << 3))) = vv; }
      STC(0, v0) STC(1, v1) STC(2, v2) STC(3, v3)
      STC(4, v4) STC(5, v5) STC(6, v6) STC(7, v7)
      #undef STC
    }
    __syncthreads();

    // ---- acc init from xu (bias already folded) ----
    f32x4 acc;
    acc[0] = __uint_as_float(pxu.x << 16);
    acc[1] = __uint_as_float(pxu.x & 0xffff0000u);
    acc[2] = __uint_as_float(pxu.y << 16);
    acc[3] = __uint_as_float(pxu.y & 0xffff0000u);

    // ---- gates += h @ V  (K = 1024) ----
    #pragma unroll 1
    for (int kk0 = 0; kk0 < 32; kk0 += 8) {
      bf16x8 bfr[8];
      #pragma unroll
      for (int j = 0; j < 8; ++j)
        bfr[j] = *(const bf16x8*)(wp + (size_t)(kk0 + j) * 32);
      #pragma unroll
      for (int j = 0; j < 8; ++j) {
        const int k = (kk0 + j) * 32 + klane;
        const bf16x8 af = *(const bf16x8*)(sh + arow * 1024 + (k ^ xr_a));
        acc = __builtin_amdgcn_mfma_f32_16x16x32_bf16(af, bfr[j], acc, 0, 0, 0);
      }
    }
    __syncthreads();   // all LDS h reads done -> overlay is safe

    #pragma unroll
    for (int i = 0; i < 4; ++i)
      gl[(bm + i) * 68 + n * 16 + cit] = acc[i];
    __syncthreads();

    { // ---- combine: per-thread one (b, j) ----
      const float gi = gl[bl * 68 +  0 + cj];
      const float gf = gl[bl * 68 + 16 + cj];
      const float gg = gl[bl * 68 + 32 + cj];
      const float go = gl[bl * 68 + 48 + cj];
      const float i_ = sigm(gi), f_ = sigm(gf), g_ = sigm(gg), o_ = sigm(go);
      c_state = f_ * c_state + i_ * g_;
      const float h = o_ * tanhf(c_state);
      const int b = b0 + bl;
      out[((size_t)b << 19) + (size_t)t * H_ + base + cj] = h;
      const unsigned hv = (unsigned)f2bf(h);
      short* hdst = hb + (size_t)((t + 1) & 1) * (B_ * H_) + (size_t)b * H_ + base + cj;
      asm volatile("global_store_short %0, %1, off sc0 sc1" :: "v"(hdst), "v"(hv) : "memory");
      if (t == T_ - 1) {
        out[(size_t)B_ * T_ * H_ + (size_t)b * H_ + base + cj] = h;
        out[(size_t)B_ * T_ * H_ + (size_t)B_ * H_ + (size_t)b * H_ + base + cj] = c_state;
      }
    }
    // ---- flag barrier (no RMW): drain h stores, publish flag, poll 64 flags ----
    asm volatile("s_waitcnt vmcnt(0)" ::: "memory");
    __syncthreads();
    if (t + 1 < T_) {
      if (tid < 64) {
        if (tid == 0) {
          const unsigned fv = (unsigned)(t + 1);
          asm volatile("global_store_dword %0, %1, off sc0 sc1" :: "v"(myflag), "v"(fv) : "memory");
        }
        unsigned v;
        do {
          asm volatile("s_sleep 2" ::: "memory");
          asm volatile("global_load_dword %0, %1, off sc0 sc1" : "=v"(v) : "v"(pollp) : "memory");
          asm volatile("s_waitcnt vmcnt(0)" ::: "memory");
        } while (!__all((int)v > t));
      }
      __syncthreads();
    }
  }
}

extern "C" void kernel_launch(void* const* d_in, const int* in_sizes, int n_in,
                              void* d_out, int out_size, void* d_ws, size_t ws_size,
                              hipStream_t stream)
{
  const float* x  = (const float*)d_in[0];
  const float* U0 = (const float*)d_in[1];
  const float* Vg0 = (const float*)d_in[2];
  const float* bg0 = (const float*)d_in[3];
  const float* U1 = (const float*)d_in[4];
  const float* Vg1 = (const float*)d_in[5];
  const float* bg1 = (const float*)d_in[6];
  const float* U2 = (const float*)d_in[7];
  const float* Vg2 = (const float*)d_in[8];
  const float* bg2 = (const float*)d_in[9];
  const float* U3 = (const float*)d_in[10];
  const float* Vg3 = (const float*)d_in[11];
  const float* bg3 = (const float*)d_in[12];

  if (ws_size < WS_NEED) return;  // diagnostic: leaves d_out poisoned

  char* ws = (char*)d_ws;
  short* Wt = (short*)(ws + OFF_WT);
  short* xu = (short*)(ws + OFF_XU);
  short* hb = (short*)(ws + OFF_HB);
  unsigned* flg = (unsigned*)(ws + OFF_FLG);

  hipMemsetAsync(ws + OFF_HB, 0, (size_t)262144 + 8192, stream);
  pack_w_kernel<<<dim3(64, 24), 256, 0, stream>>>(U0, U1, U2, U3, Vg0, Vg1, Vg2, Vg3, Wt);
  xu_gemm<<<dim3(16, 512), 512, 0, stream>>>(x, bg0, bg1, bg2, bg3, Wt, xu);
  lstm_rec<<<dim3(GROUPS * GBLK), 512, 0, stream>>>(Wt, xu, hb, flg, (float*)d_out);
}

// Round 4
// 3059.504 us; speedup vs baseline: 2.1526x; 2.0834x over previous
//
#include <hip/hip_runtime.h>
#include <stdint.h>

#define B_  64
#define T_  512
#define I_  512
#define H_  1024
#define G4  4096
#define KW  1536   // rows of W_t = I_ + H_

#define GROUPS 4
#define GBLK   64    // col-blocks per group
#define MBR    16    // batch rows per group

#define LDS_BYTES 163840

typedef __attribute__((ext_vector_type(8))) short bf16x8;
typedef __attribute__((ext_vector_type(4))) float f32x4;

// ---- ws layout (bytes) ----
#define OFF_WT   ((size_t)0)                        // 4096*1536*2 = 12,582,912
#define OFF_XU   ((size_t)(16u << 20))              // 512*4096*64*2 = 268,435,456
#define OFF_HB   (OFF_XU + (size_t)268435456)       // 2*64*1024*2 = 262,144
#define OFF_FLG  (OFF_HB + (size_t)262144)          // 4 groups * 64 flags * 64B = 16384
#define WS_NEED  (OFF_FLG + (size_t)16384)

__device__ __forceinline__ unsigned short f2bf(float x) {
  unsigned u = __float_as_uint(x);
  u += 0x7FFFu + ((u >> 16) & 1u);        // RNE
  return (unsigned short)(u >> 16);
}
__device__ __forceinline__ float sigm(float x) {
  return 1.0f / (1.0f + __expf(-x));
}

// ============ kernel 0: pack [U;V] -> W_t[col][k] bf16 (transposed) ============
__global__ __launch_bounds__(256) void pack_w_kernel(
    const float* __restrict__ U0, const float* __restrict__ U1,
    const float* __restrict__ U2, const float* __restrict__ U3,
    const float* __restrict__ V0, const float* __restrict__ V1,
    const float* __restrict__ V2, const float* __restrict__ V3,
    short* __restrict__ Wt)
{
  __shared__ short sl[64][65];
  const int c0 = blockIdx.x * 64;         // col tile (within one gate: 64 | 1024)
  const int k0 = blockIdx.y * 64;         // k tile (within U or V: 64 | 512)
  const int g  = c0 >> 10;
  const int h0 = c0 & 1023;
  const float* srcU = (g == 0 ? U0 : g == 1 ? U1 : g == 2 ? U2 : U3);
  const float* srcV = (g == 0 ? V0 : g == 1 ? V1 : g == 2 ? V2 : V3);
  const float* src  = (k0 < 512) ? (srcU + (size_t)k0 * H_)
                                 : (srcV + (size_t)(k0 - 512) * H_);
  const int tid = threadIdx.x;
  const int cl = tid & 63;
  const int r4 = tid >> 6;
  #pragma unroll
  for (int r = 0; r < 16; ++r) {
    const int kl = r * 4 + r4;
    sl[kl][cl] = (short)f2bf(src[(size_t)kl * H_ + h0 + cl]);
  }
  __syncthreads();
  #pragma unroll
  for (int r = 0; r < 16; ++r) {
    const int cl2 = r * 4 + r4;
    Wt[(size_t)(c0 + cl2) * KW + k0 + cl] = sl[cl][cl2];
  }
}

// ============ kernel 1: xu[t][gc][b] = bf16( x_t @ U + bias ) ============
__global__ __launch_bounds__(512) void xu_gemm(
    const float* __restrict__ x,
    const float* __restrict__ b0g, const float* __restrict__ b1g,
    const float* __restrict__ b2g, const float* __restrict__ b3g,
    const short* __restrict__ Wt, short* __restrict__ xu)
{
  __shared__ short sa[64 * 512];          // A tile (64 b-rows x 512 k) bf16, swizzled
  const int t  = blockIdx.y;
  const int cb = blockIdx.x * 256;        // col base (within one gate: 256 | 1024)
  const int tid = threadIdx.x;

  { // stage x[b][t][:] -> sa (fp32 -> bf16)
    const int b  = tid >> 3;
    const int kc = (tid & 7) * 64;
    const float* xp = x + ((size_t)b * T_ + t) * I_ + kc;
    const int xr = (b & 7) << 3;
    #pragma unroll
    for (int i = 0; i < 16; ++i) {
      const float4 v = *(const float4*)(xp + i * 4);
      const int k = kc + i * 4;
      uint2 pk;
      pk.x = (unsigned)f2bf(v.x) | ((unsigned)f2bf(v.y) << 16);
      pk.y = (unsigned)f2bf(v.z) | ((unsigned)f2bf(v.w) << 16);
      *(uint2*)(sa + b * 512 + (k ^ xr)) = pk;
    }
  }
  __syncthreads();

  const int w = tid >> 6, l = tid & 63;
  const int m  = w & 3;                   // 4 m-tiles (batch)
  const int nh = w >> 2;                  // 2 halves of 16 n-tiles
  const int cit = l & 15;
  const int klane = (l >> 4) * 8;
  const int arow = m * 16 + cit;
  const int xrr = (arow & 7) << 3;
  const int bm = m * 16 + ((l >> 4) << 2);

  const int gate = cb >> 10;
  const float* bias = (gate == 0 ? b0g : gate == 1 ? b1g : gate == 2 ? b2g : b3g);

  f32x4 acc[8];
  #pragma unroll
  for (int n = 0; n < 8; ++n) {
    const int gc = cb + (nh * 8 + n) * 16 + cit;
    const float bv = bias[gc & 1023];
    acc[n] = (f32x4){bv, bv, bv, bv};
  }

  for (int kk = 0; kk < 16; ++kk) {
    const int k = kk * 32 + klane;
    const bf16x8 af = *(const bf16x8*)(sa + arow * 512 + (k ^ xrr));
    #pragma unroll
    for (int n = 0; n < 8; ++n) {
      const int gc = cb + (nh * 8 + n) * 16 + cit;
      const bf16x8 bf = *(const bf16x8*)(Wt + (size_t)gc * KW + k);
      acc[n] = __builtin_amdgcn_mfma_f32_16x16x32_bf16(af, bf, acc[n], 0, 0, 0);
    }
  }

  #pragma unroll
  for (int n = 0; n < 8; ++n) {
    const int gc = cb + (nh * 8 + n) * 16 + cit;
    uint2 pk;
    pk.x = (unsigned)f2bf(acc[n][0]) | ((unsigned)f2bf(acc[n][1]) << 16);
    pk.y = (unsigned)f2bf(acc[n][2]) | ((unsigned)f2bf(acc[n][3]) << 16);
    *(uint2*)(xu + ((size_t)t * G4 + gc) * 64 + bm) = pk;
  }
}

// ============ kernel 2: persistent recurrence, V-weights LDS-resident ============
__global__ __launch_bounds__(512, 1) void lstm_rec(
    const short* __restrict__ Wt, const short* __restrict__ xu,
    short* __restrict__ hb, unsigned* __restrict__ flg, float* __restrict__ out)
{
  extern __shared__ char smem[];
  short* sw = (short*)smem;                        // [64 gc][1024 K] bf16 swizzled, 128 KiB
  short* sh = (short*)(smem + 131072);             // [16 rows][1024 K] bf16 swizzled, 32 KiB
  float* gl = (float*)(smem + 131072);             // overlay: [16 r][2 ks][68] f32 (8704 B)
  short* hst = (short*)(smem + 131072 + 12288);    // overlay: h staging 512 B

  const int tid = threadIdx.x;
  const int blk = blockIdx.x;
  const int g   = blk >> 6;                // group (16 batch rows)
  const int bi  = blk & 63;
  const int base = bi * 16;                // 16 h-cols per block
  const int b0  = g * MBR;

  const int w = tid >> 6, l = tid & 63;
  const int ct = w & 3;                    // col-tile == gate index
  const int ks = w >> 2;                   // K half (0: 0..511, 1: 512..1023)
  const int cit = l & 15;
  const int l16 = l >> 4;                  // 0..3
  const int klane = l16 * 8;
  const int gcl = ct * 16 + cit;           // local gate-col 0..63
  const int gc  = ct * 1024 + base + cit;  // global gate-col
  const int arow = cit;                    // A-fragment row

  // ---- one-time: load this block's V slice (K=512..1535 of Wt) into LDS ----
  #pragma unroll
  for (int i = 0; i < 16; ++i) {
    const int idx = i * 512 + tid;
    const int lc = idx >> 7;               // local gate-col 0..63
    const int kc = (idx & 127) * 8;        // K offset (shorts)
    const int gcg = (lc >> 4) * 1024 + base + (lc & 15);
    const int4 v = *(const int4*)(Wt + (size_t)gcg * KW + 512 + kc);
    *(int4*)(sw + lc * 1024 + (kc ^ ((lc & 7) << 3))) = v;
  }

  unsigned* myflag = flg + (size_t)g * 1024 + (size_t)bi * 16;
  unsigned* pollp  = flg + (size_t)g * 1024 + (size_t)l * 16;

  float c_state = 0.0f;

  // prologue xu prefetch (ks==0 waves consume xu)
  uint2 pxu = make_uint2(0u, 0u);
  if (ks == 0)
    pxu = *(const uint2*)(xu + ((size_t)0 * G4 + gc) * 64 + b0 + l16 * 4);

  for (int t = 0; t < T_; ++t) {
    { // ---- stage h(t) (device-coherent) into LDS, swizzled, K-major ----
      const short* hsrc = hb + (size_t)(t & 1) * (B_ * H_) + (size_t)b0 * H_;
      int4 v0, v1, v2, v3;
      const short* p;
      #define LDC(ii, vv) \
        p = hsrc + (size_t)(((ii) * 512 + tid) * 8); \
        asm volatile("global_load_dwordx4 %0, %1, off sc0 sc1" : "=&v"(vv) : "v"(p));
      LDC(0, v0) LDC(1, v1) LDC(2, v2) LDC(3, v3)
      #undef LDC
      asm volatile("s_waitcnt vmcnt(0)" ::: "memory");
      __builtin_amdgcn_sched_barrier(0);
      #define STC(ii, vv) { const int f = (ii) * 512 + tid; const int row = f >> 7; \
        const int k0 = (f & 127) * 8; \
        *(int4*)(sh + row * 1024 + (k0 ^ ((row & 7) << 3))) = vv; }
      STC(0, v0) STC(1, v1) STC(2, v2) STC(3, v3)
      #undef STC
    }
    __syncthreads();

    // ---- acc init: ks==0 waves take xu (bias folded), ks==1 start at 0 ----
    f32x4 acc;
    if (ks == 0) {
      acc[0] = __uint_as_float(pxu.x << 16);
      acc[1] = __uint_as_float(pxu.x & 0xffff0000u);
      acc[2] = __uint_as_float(pxu.y << 16);
      acc[3] = __uint_as_float(pxu.y & 0xffff0000u);
    } else {
      acc = (f32x4){0.0f, 0.0f, 0.0f, 0.0f};
    }

    // ---- gates += h @ V, all operands in LDS ----
    const int kb = ks * 512;
    #pragma unroll 4
    for (int kk = 0; kk < 16; ++kk) {
      const int kl = kb + kk * 32 + klane;
      const bf16x8 af = *(const bf16x8*)(sh + arow * 1024 + (kl ^ ((arow & 7) << 3)));
      const bf16x8 bf = *(const bf16x8*)(sw + gcl * 1024 + (kl ^ ((gcl & 7) << 3)));
      acc = __builtin_amdgcn_mfma_f32_16x16x32_bf16(af, bf, acc, 0, 0, 0);
    }
    __syncthreads();   // all sh reads done -> overlay region is safe

    #pragma unroll
    for (int i = 0; i < 4; ++i)
      gl[(l16 * 4 + i) * 136 + ks * 68 + gcl] = acc[i];
    __syncthreads();

    if (tid < 256) { // ---- combine: thread = (row, cj) ----
      const int row = tid >> 4, cj = tid & 15;
      const float* gr = gl + row * 136;
      const float gi = gr[ 0 + cj] + gr[68 +  0 + cj];
      const float gf = gr[16 + cj] + gr[68 + 16 + cj];
      const float gg = gr[32 + cj] + gr[68 + 32 + cj];
      const float go = gr[48 + cj] + gr[68 + 48 + cj];
      const float i_ = sigm(gi), f_ = sigm(gf), g_ = sigm(gg), o_ = sigm(go);
      c_state = f_ * c_state + i_ * g_;
      const float h = o_ * tanhf(c_state);
      const int b = b0 + row;
      out[((size_t)b << 19) + (size_t)t * H_ + base + cj] = h;
      hst[row * 16 + cj] = (short)f2bf(h);
      if (t == T_ - 1) {
        out[(size_t)B_ * T_ * H_ + (size_t)b * H_ + base + cj] = h;
        out[(size_t)B_ * T_ * H_ + (size_t)B_ * H_ + (size_t)b * H_ + base + cj] = c_state;
      }
    }
    __syncthreads();

    if (t + 1 < T_) {
      // ---- publish h (coherent dword stores), flag, poll ----
      if (tid < 32) {
        const int r = tid >> 1, half = tid & 1;
        const int4 hv = *(const int4*)(hst + r * 16 + half * 8);
        short* hdst = hb + (size_t)((t + 1) & 1) * (B_ * H_)
                      + (size_t)(b0 + r) * H_ + base + half * 8;
        asm volatile("global_store_dword %0, %1, off sc0 sc1"           :: "v"(hdst), "v"(hv.x) : "memory");
        asm volatile("global_store_dword %0, %1, off offset:4 sc0 sc1"  :: "v"(hdst), "v"(hv.y) : "memory");
        asm volatile("global_store_dword %0, %1, off offset:8 sc0 sc1"  :: "v"(hdst), "v"(hv.z) : "memory");
        asm volatile("global_store_dword %0, %1, off offset:12 sc0 sc1" :: "v"(hdst), "v"(hv.w) : "memory");
      }
      if (tid < 64) {
        asm volatile("s_waitcnt vmcnt(0)" ::: "memory");
        if (tid == 0) {
          const unsigned fv = (unsigned)(t + 1);
          asm volatile("global_store_dword %0, %1, off sc0 sc1" :: "v"(myflag), "v"(fv) : "memory");
        }
      }
      // prefetch next xu under the barrier latency
      if (ks == 0)
        pxu = *(const uint2*)(xu + ((size_t)(t + 1) * G4 + gc) * 64 + b0 + l16 * 4);
      if (tid < 64) {
        unsigned v;
        for (;;) {
          asm volatile("global_load_dword %0, %1, off sc0 sc1" : "=v"(v) : "v"(pollp) : "memory");
          asm volatile("s_waitcnt vmcnt(0)" ::: "memory");
          if (__all((int)v > t)) break;
          asm volatile("s_sleep 1" ::: "memory");
        }
      }
      __syncthreads();
    }
  }
}

extern "C" void kernel_launch(void* const* d_in, const int* in_sizes, int n_in,
                              void* d_out, int out_size, void* d_ws, size_t ws_size,
                              hipStream_t stream)
{
  const float* x  = (const float*)d_in[0];
  const float* U0 = (const float*)d_in[1];
  const float* Vg0 = (const float*)d_in[2];
  const float* bg0 = (const float*)d_in[3];
  const float* U1 = (const float*)d_in[4];
  const float* Vg1 = (const float*)d_in[5];
  const float* bg1 = (const float*)d_in[6];
  const float* U2 = (const float*)d_in[7];
  const float* Vg2 = (const float*)d_in[8];
  const float* bg2 = (const float*)d_in[9];
  const float* U3 = (const float*)d_in[10];
  const float* Vg3 = (const float*)d_in[11];
  const float* bg3 = (const float*)d_in[12];

  if (ws_size < WS_NEED) return;  // diagnostic: leaves d_out poisoned

  char* ws = (char*)d_ws;
  short* Wt = (short*)(ws + OFF_WT);
  short* xu = (short*)(ws + OFF_XU);
  short* hb = (short*)(ws + OFF_HB);
  unsigned* flg = (unsigned*)(ws + OFF_FLG);

  (void)hipFuncSetAttribute((const void*)lstm_rec,
                      hipFuncAttributeMaxDynamicSharedMemorySize, LDS_BYTES);

  (void)hipMemsetAsync(ws + OFF_HB, 0, (size_t)262144 + 16384, stream);
  pack_w_kernel<<<dim3(64, 24), 256, 0, stream>>>(U0, U1, U2, U3, Vg0, Vg1, Vg2, Vg3, Wt);
  xu_gemm<<<dim3(16, 512), 512, 0, stream>>>(x, bg0, bg1, bg2, bg3, Wt, xu);
  lstm_rec<<<dim3(GROUPS * GBLK), 512, LDS_BYTES, stream>>>(Wt, xu, hb, flg, (float*)d_out);
}

// Round 5
// 1774.490 us; speedup vs baseline: 3.7114x; 1.7242x over previous
//
#include <hip/hip_runtime.h>
#include <stdint.h>

#define B_  64
#define T_  512
#define I_  512
#define H_  1024
#define G4  4096
#define KW  1536   // rows of W_t = I_ + H_

#define GROUPS 4
#define GBLK   64    // col-blocks per group
#define MBR    16    // batch rows per group

#define LDS_BYTES 163840

typedef __attribute__((ext_vector_type(8))) short bf16x8;
typedef __attribute__((ext_vector_type(4))) float f32x4;

// ---- ws layout (bytes) ----
#define OFF_WT   ((size_t)0)                        // 4096*1536*2 = 12,582,912
#define OFF_XB   ((size_t)(16u << 20))              // x bf16: 64*512*512*2 = 33,554,432
#define OFF_HB   (OFF_XB + (size_t)33554432)        // 2*64*1024*2 = 262,144
#define OFF_FLG  (OFF_HB + (size_t)262144)          // 4 groups * 64 flags * 64B
#define WS_NEED  (OFF_FLG + (size_t)16384)

__device__ __forceinline__ unsigned short f2bf(float x) {
  unsigned u = __float_as_uint(x);
  u += 0x7FFFu + ((u >> 16) & 1u);        // RNE
  return (unsigned short)(u >> 16);
}
__device__ __forceinline__ float sigm(float x) {
  return 1.0f / (1.0f + __expf(-x));
}

// ============ kernel 0: pack [U;V] -> W_t[col][k] bf16 (transposed) ============
__global__ __launch_bounds__(256) void pack_w_kernel(
    const float* __restrict__ U0, const float* __restrict__ U1,
    const float* __restrict__ U2, const float* __restrict__ U3,
    const float* __restrict__ V0, const float* __restrict__ V1,
    const float* __restrict__ V2, const float* __restrict__ V3,
    short* __restrict__ Wt)
{
  __shared__ short sl[64][65];
  const int c0 = blockIdx.x * 64;         // col tile (within one gate: 64 | 1024)
  const int k0 = blockIdx.y * 64;         // k tile (within U or V: 64 | 512)
  const int g  = c0 >> 10;
  const int h0 = c0 & 1023;
  const float* srcU = (g == 0 ? U0 : g == 1 ? U1 : g == 2 ? U2 : U3);
  const float* srcV = (g == 0 ? V0 : g == 1 ? V1 : g == 2 ? V2 : V3);
  const float* src  = (k0 < 512) ? (srcU + (size_t)k0 * H_)
                                 : (srcV + (size_t)(k0 - 512) * H_);
  const int tid = threadIdx.x;
  const int cl = tid & 63;
  const int r4 = tid >> 6;
  #pragma unroll
  for (int r = 0; r < 16; ++r) {
    const int kl = r * 4 + r4;
    sl[kl][cl] = (short)f2bf(src[(size_t)kl * H_ + h0 + cl]);
  }
  __syncthreads();
  #pragma unroll
  for (int r = 0; r < 16; ++r) {
    const int cl2 = r * 4 + r4;
    Wt[(size_t)(c0 + cl2) * KW + k0 + cl] = sl[cl][cl2];
  }
}

// ============ kernel 1: x fp32 -> bf16 ============
__global__ __launch_bounds__(256) void xcvt(
    const float* __restrict__ x, short* __restrict__ xb)
{
  const int nt = 524288;  // 2048 blocks * 256 threads
  const int idx = blockIdx.x * 256 + threadIdx.x;
  #pragma unroll
  for (int i = 0; i < 8; ++i) {
    const int j = idx + i * nt;           // 4,194,304 float4 total
    const float4 v = ((const float4*)x)[j];
    uint2 pk;
    pk.x = (unsigned)f2bf(v.x) | ((unsigned)f2bf(v.y) << 16);
    pk.y = (unsigned)f2bf(v.z) | ((unsigned)f2bf(v.w) << 16);
    ((uint2*)xb)[j] = pk;
  }
}

// ============ kernel 2: persistent recurrence, fused x@U, fragment LDS ============
__global__ __launch_bounds__(512, 1) void lstm_rec(
    const short* __restrict__ Wt, const short* __restrict__ xb,
    const float* __restrict__ b0g, const float* __restrict__ b1g,
    const float* __restrict__ b2g, const float* __restrict__ b3g,
    short* __restrict__ hb, unsigned* __restrict__ flg, float* __restrict__ out)
{
  extern __shared__ char smem[];
  short* sw = (short*)smem;                 // 128 KiB V frags: unit (ct2*16+kk)*64+l, 16B each
  short* sh = (short*)(smem + 131072);      // 32 KiB h/x frags: unit kk*64+slot
  float* gl = (float*)(smem + 131072);      // overlay [16][137] f32 (8768 B)

  const int tid = threadIdx.x;
  const int blk = blockIdx.x;
  const int g   = blk >> 6;                 // group (16 batch rows)
  const int bi  = blk & 63;
  const int base = bi * 16;                 // 16 h-cols per block
  const int b0  = g * MBR;

  const int w = tid >> 6, l = tid & 63;
  const int ct = w & 3;                     // gate index
  const int ks = w >> 2;                    // K half
  const int ct2 = ct * 2 + ks;
  const int cit = l & 15;
  const int l16 = l >> 4;
  const int slot_r = (cit << 2) | l16;      // fragment read slot
  const int gcl = ct * 16 + cit;

  // ---- one-time: V slice -> sw in fragment order ----
  for (int i = 0; i < 16; ++i) {
    const int u = i * 512 + tid;            // 8192 units of 16 B
    const int c2 = u >> 10;
    const int kk = (u >> 6) & 15;
    const int ll = u & 63;
    const int col = (c2 >> 1) * 1024 + base + (ll & 15);
    const int kg  = 512 + (c2 & 1) * 512 + kk * 32 + ((ll >> 4) << 3);
    const int4 v = *(const int4*)(Wt + (size_t)col * KW + kg);
    *(int4*)(sw + (size_t)u * 8) = v;
  }

  // ---- one-time: U fragments -> registers (32 VGPRs) ----
  bf16x8 ufr[8];
  {
    const int col = ct * 1024 + base + cit;
    #pragma unroll
    for (int j = 0; j < 8; ++j)
      ufr[j] = *(const bf16x8*)(Wt + (size_t)col * KW + ks * 256 + j * 32 + l16 * 8);
  }

  const float* biasp = (ct == 0 ? b0g : ct == 1 ? b1g : ct == 2 ? b2g : b3g);
  const float bv_ = (ks == 0) ? biasp[base + cit] : 0.0f;

  unsigned* myflag = flg + (size_t)g * 1024 + (size_t)bi * 16;
  unsigned* pollp  = flg + (size_t)g * 1024 + (size_t)l * 16;

  const int crow = tid >> 4;                // combine row (tid<256)
  const int ccj  = tid & 15;

  float c_state = 0.0f;

  // ---- prologue: stage x(0), produce xu(0) ----
  #pragma unroll
  for (int i = 0; i < 2; ++i) {
    const int f = i * 512 + tid;
    const int row = f >> 6;
    const int k0 = (f & 63) * 8;
    const int4 v = *(const int4*)(xb + ((size_t)(b0 + row) * T_ + 0) * I_ + k0);
    *(int4*)(sh + ((k0 >> 5) * 64 + ((row << 2) | ((k0 >> 3) & 3))) * 8) = v;
  }
  __syncthreads();
  f32x4 xacc = (f32x4){bv_, bv_, bv_, bv_};
  #pragma unroll
  for (int j = 0; j < 8; ++j) {
    const bf16x8 af = *(const bf16x8*)(sh + ((ks * 8 + j) * 64 + slot_r) * 8);
    xacc = __builtin_amdgcn_mfma_f32_16x16x32_bf16(af, ufr[j], xacc, 0, 0, 0);
  }
  __syncthreads();   // xu(0) reads done before phase A overwrites sh

  for (int t = 0; t < T_; ++t) {
    { // ---- A: stage h(t) (device-coherent) -> sh fragment order ----
      const short* hsrc = hb + (size_t)(t & 1) * (B_ * H_);
      int4 v0, v1, v2, v3;
      #define LDC(ii, vv) { \
        const short* p = hsrc + (size_t)(b0 + (((ii) * 512 + tid) >> 7)) * H_ \
                         + ((((ii) * 512 + tid) & 127) * 8); \
        asm volatile("global_load_dwordx4 %0, %1, off sc0 sc1" : "=&v"(vv) : "v"(p)); }
      LDC(0, v0) LDC(1, v1) LDC(2, v2) LDC(3, v3)
      #undef LDC
      asm volatile("s_waitcnt vmcnt(0)" ::: "memory");
      __builtin_amdgcn_sched_barrier(0);
      #define STC(ii, vv) { const int f = (ii) * 512 + tid; const int row = f >> 7; \
        const int k0 = (f & 127) * 8; \
        *(int4*)(sh + ((k0 >> 5) * 64 + ((row << 2) | ((k0 >> 3) & 3))) * 8) = vv; }
      STC(0, v0) STC(1, v1) STC(2, v2) STC(3, v3)
      #undef STC
    }
    __syncthreads();

    // ---- B: gates = xu(t) + h @ V  (fragment-linear ds_reads) ----
    f32x4 acc = xacc;
    #pragma unroll
    for (int j = 0; j < 16; ++j) {
      const bf16x8 af = *(const bf16x8*)(sh + ((ks * 16 + j) * 64 + slot_r) * 8);
      const bf16x8 bf = *(const bf16x8*)(sw + ((ct2 * 16 + j) * 64 + l) * 8);
      acc = __builtin_amdgcn_mfma_f32_16x16x32_bf16(af, bf, acc, 0, 0, 0);
    }
    __syncthreads();   // sh reads done -> overlay safe

    // ---- C: cross-(ct,ks) exchange via gl ----
    #pragma unroll
    for (int i = 0; i < 4; ++i)
      gl[(l16 * 4 + i) * 137 + ks * 68 + gcl] = acc[i];
    __syncthreads();

    // ---- D: combine + publish h ----
    float hval = 0.0f;
    if (tid < 256) {
      const float* gr = gl + crow * 137;
      const float gi = gr[ 0 + ccj] + gr[68 +  0 + ccj];
      const float gf = gr[16 + ccj] + gr[68 + 16 + ccj];
      const float gg = gr[32 + ccj] + gr[68 + 32 + ccj];
      const float go = gr[48 + ccj] + gr[68 + 48 + ccj];
      const float i_ = sigm(gi), f_ = sigm(gf), g_ = sigm(gg), o_ = sigm(go);
      c_state = f_ * c_state + i_ * g_;
      hval = o_ * tanhf(c_state);
      if (t + 1 < T_) {
        const unsigned hv = (unsigned)f2bf(hval);
        short* hdst = hb + (size_t)((t + 1) & 1) * (B_ * H_)
                      + (size_t)(b0 + crow) * H_ + base + ccj;
        asm volatile("global_store_short %0, %1, off sc0 sc1" :: "v"(hdst), "v"(hv) : "memory");
      }
    }
    asm volatile("s_waitcnt vmcnt(0)" ::: "memory");   // per-wave drain of h stores
    __syncthreads();                                    // all waves drained (gl reads done too)
    if (t + 1 < T_ && tid == 0) {
      const unsigned fv = (unsigned)(t + 1);
      asm volatile("global_store_dword %0, %1, off sc0 sc1" :: "v"(myflag), "v"(fv) : "memory");
    }

    // out[] stores off the critical path (lazy, normal cache path)
    if (tid < 256) {
      out[((size_t)(b0 + crow) << 19) + (size_t)t * H_ + base + ccj] = hval;
      if (t == T_ - 1) {
        out[(size_t)B_ * T_ * H_ + (size_t)(b0 + crow) * H_ + base + ccj] = hval;
        out[(size_t)B_ * T_ * H_ + (size_t)B_ * H_ + (size_t)(b0 + crow) * H_ + base + ccj] = c_state;
      }
    }

    if (t + 1 < T_) {
      // ---- E: stage x(t+1) -> sh (fills poll slack) ----
      #pragma unroll
      for (int i = 0; i < 2; ++i) {
        const int f = i * 512 + tid;
        const int row = f >> 6;
        const int k0 = (f & 63) * 8;
        const int4 v = *(const int4*)(xb + ((size_t)(b0 + row) * T_ + (t + 1)) * I_ + k0);
        *(int4*)(sh + ((k0 >> 5) * 64 + ((row << 2) | ((k0 >> 3) & 3))) * 8) = v;
      }
      __syncthreads();

      // ---- F: xu(t+1) = bias + x(t+1) @ U (in poll slack) ----
      xacc = (f32x4){bv_, bv_, bv_, bv_};
      #pragma unroll
      for (int j = 0; j < 8; ++j) {
        const bf16x8 af = *(const bf16x8*)(sh + ((ks * 8 + j) * 64 + slot_r) * 8);
        xacc = __builtin_amdgcn_mfma_f32_16x16x32_bf16(af, ufr[j], xacc, 0, 0, 0);
      }

      // ---- G: barrier poll ----
      if (tid < 64) {
        unsigned v;
        for (;;) {
          asm volatile("global_load_dword %0, %1, off sc0 sc1" : "=v"(v) : "v"(pollp) : "memory");
          asm volatile("s_waitcnt vmcnt(0)" ::: "memory");
          if (__all((int)v > t)) break;
          asm volatile("s_sleep 1" ::: "memory");
        }
      }
      __syncthreads();   // implicit lgkm/vm drain orders F's reads before next A's writes
    }
  }
}

extern "C" void kernel_launch(void* const* d_in, const int* in_sizes, int n_in,
                              void* d_out, int out_size, void* d_ws, size_t ws_size,
                              hipStream_t stream)
{
  const float* x  = (const float*)d_in[0];
  const float* U0 = (const float*)d_in[1];
  const float* Vg0 = (const float*)d_in[2];
  const float* bg0 = (const float*)d_in[3];
  const float* U1 = (const float*)d_in[4];
  const float* Vg1 = (const float*)d_in[5];
  const float* bg1 = (const float*)d_in[6];
  const float* U2 = (const float*)d_in[7];
  const float* Vg2 = (const float*)d_in[8];
  const float* bg2 = (const float*)d_in[9];
  const float* U3 = (const float*)d_in[10];
  const float* Vg3 = (const float*)d_in[11];
  const float* bg3 = (const float*)d_in[12];

  if (ws_size < WS_NEED) return;  // diagnostic: leaves d_out poisoned

  char* ws = (char*)d_ws;
  short* Wt = (short*)(ws + OFF_WT);
  short* xb = (short*)(ws + OFF_XB);
  short* hb = (short*)(ws + OFF_HB);
  unsigned* flg = (unsigned*)(ws + OFF_FLG);

  (void)hipFuncSetAttribute((const void*)lstm_rec,
                      hipFuncAttributeMaxDynamicSharedMemorySize, LDS_BYTES);

  (void)hipMemsetAsync(ws + OFF_HB, 0, (size_t)262144 + 16384, stream);
  pack_w_kernel<<<dim3(64, 24), 256, 0, stream>>>(U0, U1, U2, U3, Vg0, Vg1, Vg2, Vg3, Wt);
  xcvt<<<dim3(2048), 256, 0, stream>>>(x, xb);
  lstm_rec<<<dim3(GROUPS * GBLK), 512, LDS_BYTES, stream>>>(
      Wt, xb, bg0, bg1, bg2, bg3, hb, flg, (float*)d_out);
}

// Round 6
// 1730.649 us; speedup vs baseline: 3.8054x; 1.0253x over previous
//
#include <hip/hip_runtime.h>
#include <stdint.h>

#define B_  64
#define T_  512
#define I_  512
#define H_  1024
#define G4  4096
#define KW  1536   // rows of W_t = I_ + H_

#define GROUPS 4
#define GBLK   64    // col-blocks per group
#define MBR    16    // batch rows per group

#define LDS_BYTES 163840

typedef __attribute__((ext_vector_type(8))) short bf16x8;
typedef __attribute__((ext_vector_type(4))) float f32x4;

// ---- ws layout (bytes) ----
#define OFF_WT   ((size_t)0)                        // 4096*1536*2 = 12,582,912
#define OFF_XB   ((size_t)(16u << 20))              // x bf16: 64*512*512*2 = 33,554,432
#define OFF_HB   (OFF_XB + (size_t)33554432)        // 2*64*1024*2 = 262,144
#define OFF_FLG  (OFF_HB + (size_t)262144)          // 4 groups * 64 flags * 64B
#define WS_NEED  (OFF_FLG + (size_t)16384)

__device__ __forceinline__ unsigned short f2bf(float x) {
  unsigned u = __float_as_uint(x);
  u += 0x7FFFu + ((u >> 16) & 1u);        // RNE
  return (unsigned short)(u >> 16);
}
__device__ __forceinline__ float sigm(float x) {
  return 1.0f / (1.0f + __expf(-x));
}

// ============ kernel 0: pack [U;V] -> W_t[col][k] bf16 (transposed) ============
__global__ __launch_bounds__(256) void pack_w_kernel(
    const float* __restrict__ U0, const float* __restrict__ U1,
    const float* __restrict__ U2, const float* __restrict__ U3,
    const float* __restrict__ V0, const float* __restrict__ V1,
    const float* __restrict__ V2, const float* __restrict__ V3,
    short* __restrict__ Wt)
{
  __shared__ short sl[64][65];
  const int c0 = blockIdx.x * 64;         // col tile (within one gate: 64 | 1024)
  const int k0 = blockIdx.y * 64;         // k tile (within U or V: 64 | 512)
  const int g  = c0 >> 10;
  const int h0 = c0 & 1023;
  const float* srcU = (g == 0 ? U0 : g == 1 ? U1 : g == 2 ? U2 : U3);
  const float* srcV = (g == 0 ? V0 : g == 1 ? V1 : g == 2 ? V2 : V3);
  const float* src  = (k0 < 512) ? (srcU + (size_t)k0 * H_)
                                 : (srcV + (size_t)(k0 - 512) * H_);
  const int tid = threadIdx.x;
  const int cl = tid & 63;
  const int r4 = tid >> 6;
  #pragma unroll
  for (int r = 0; r < 16; ++r) {
    const int kl = r * 4 + r4;
    sl[kl][cl] = (short)f2bf(src[(size_t)kl * H_ + h0 + cl]);
  }
  __syncthreads();
  #pragma unroll
  for (int r = 0; r < 16; ++r) {
    const int cl2 = r * 4 + r4;
    Wt[(size_t)(c0 + cl2) * KW + k0 + cl] = sl[cl][cl2];
  }
}

// ============ kernel 1: x fp32 -> bf16 ============
__global__ __launch_bounds__(256) void xcvt(
    const float* __restrict__ x, short* __restrict__ xb)
{
  const int nt = 524288;  // 2048 blocks * 256 threads
  const int idx = blockIdx.x * 256 + threadIdx.x;
  #pragma unroll
  for (int i = 0; i < 8; ++i) {
    const int j = idx + i * nt;           // 4,194,304 float4 total
    const float4 v = ((const float4*)x)[j];
    uint2 pk;
    pk.x = (unsigned)f2bf(v.x) | ((unsigned)f2bf(v.y) << 16);
    pk.y = (unsigned)f2bf(v.z) | ((unsigned)f2bf(v.w) << 16);
    ((uint2*)xb)[j] = pk;
  }
}

// sh fragment address (shorts): unit 0..31, slot 0..63, XOR-swizzled
#define SH_ADDR(unit, slot) ((((unit) * 64) + ((slot) ^ ((unit) & 7))) * 8)

// ============ kernel 2: persistent recurrence, fused x@U, swizzled frag LDS ============
__global__ __launch_bounds__(512, 1) void lstm_rec(
    const short* __restrict__ Wt, const short* __restrict__ xb,
    const float* __restrict__ b0g, const float* __restrict__ b1g,
    const float* __restrict__ b2g, const float* __restrict__ b3g,
    short* __restrict__ hb, unsigned* __restrict__ flg, float* __restrict__ out)
{
  extern __shared__ char smem[];
  short* sw = (short*)smem;                 // 128 KiB V frags: unit (ct2*16+kk)*64+l, 16B each
  short* sh = (short*)(smem + 131072);      // 32 KiB h/x frags, swizzled
  float* gl = (float*)(smem + 131072);      // overlay [16][138] f32 (8832 B)

  const int tid = threadIdx.x;
  const int blk = blockIdx.x;
  const int g   = blk >> 6;                 // group (16 batch rows)
  const int bi  = blk & 63;
  const int base = bi * 16;                 // 16 h-cols per block
  const int b0  = g * MBR;

  const int w = tid >> 6, l = tid & 63;
  const int ct = w & 3;                     // gate index
  const int ks = w >> 2;                    // K half
  const int ct2 = ct * 2 + ks;
  const int cit = l & 15;
  const int l16 = l >> 4;
  const int slot_r = (cit << 2) | l16;      // fragment read slot
  const int gcl = ct * 16 + cit;

  // ---- one-time: V slice -> sw in fragment order ----
  for (int i = 0; i < 16; ++i) {
    const int u = i * 512 + tid;            // 8192 units of 16 B
    const int c2 = u >> 10;
    const int kk = (u >> 6) & 15;
    const int ll = u & 63;
    const int col = (c2 >> 1) * 1024 + base + (ll & 15);
    const int kg  = 512 + (c2 & 1) * 512 + kk * 32 + ((ll >> 4) << 3);
    const int4 v = *(const int4*)(Wt + (size_t)col * KW + kg);
    *(int4*)(sw + (size_t)u * 8) = v;
  }

  // ---- one-time: U fragments -> registers (32 VGPRs) ----
  bf16x8 ufr[8];
  {
    const int col = ct * 1024 + base + cit;
    #pragma unroll
    for (int j = 0; j < 8; ++j)
      ufr[j] = *(const bf16x8*)(Wt + (size_t)col * KW + ks * 256 + j * 32 + l16 * 8);
  }

  const float* biasp = (ct == 0 ? b0g : ct == 1 ? b1g : ct == 2 ? b2g : b3g);
  const float bv_ = (ks == 0) ? biasp[base + cit] : 0.0f;

  unsigned* myflag = flg + (size_t)g * 1024 + (size_t)bi * 16;
  unsigned* pollp  = flg + (size_t)g * 1024 + (size_t)l * 16;

  const int crow = tid >> 4;                // combine row (tid<256)
  const int ccj  = tid & 15;

  // x-staging geometry for this thread (two fragments: f0=tid, f1=512+tid)
  const int xr0_row = tid >> 6,        xr0_k0 = (tid & 63) * 8;
  const int xr1_row = (512 + tid) >> 6, xr1_k0 = (tid & 63) * 8;
  const int xr0_addr = SH_ADDR(xr0_k0 >> 5, (xr0_row << 2) | ((xr0_k0 >> 3) & 3));
  const int xr1_addr = SH_ADDR(xr1_k0 >> 5, (xr1_row << 2) | ((xr1_k0 >> 3) & 3));
  const short* xsrc0 = xb + (size_t)(b0 + xr0_row) * T_ * I_ + xr0_k0;
  const short* xsrc1 = xb + (size_t)(b0 + xr1_row) * T_ * I_ + xr1_k0;

  float c_state = 0.0f;

  // ---- prologue: stage x(0), produce xu(0), prefetch x(1) ----
  *(int4*)(sh + xr0_addr) = *(const int4*)(xsrc0);
  *(int4*)(sh + xr1_addr) = *(const int4*)(xsrc1);
  __syncthreads();
  f32x4 xacc = (f32x4){bv_, bv_, bv_, bv_};
  #pragma unroll
  for (int j = 0; j < 8; ++j) {
    const int u = ks * 8 + j;
    const bf16x8 af = *(const bf16x8*)(sh + SH_ADDR(u, slot_r));
    xacc = __builtin_amdgcn_mfma_f32_16x16x32_bf16(af, ufr[j], xacc, 0, 0, 0);
  }
  int4 xr0 = *(const int4*)(xsrc0 + (size_t)1 * I_);
  int4 xr1 = *(const int4*)(xsrc1 + (size_t)1 * I_);
  __syncthreads();   // xu(0) sh reads done before phase A overwrites sh

  for (int t = 0; t < T_; ++t) {
    { // ---- A: stage h(t) (device-coherent) -> sh swizzled fragment order ----
      const short* hsrc = hb + (size_t)(t & 1) * (B_ * H_);
      int4 v0, v1, v2, v3;
      #define LDC(ii, vv) { \
        const short* p = hsrc + (size_t)(b0 + (((ii) * 512 + tid) >> 7)) * H_ \
                         + ((((ii) * 512 + tid) & 127) * 8); \
        asm volatile("global_load_dwordx4 %0, %1, off sc0 sc1" : "=&v"(vv) : "v"(p)); }
      LDC(0, v0) LDC(1, v1) LDC(2, v2) LDC(3, v3)
      #undef LDC
      asm volatile("s_waitcnt vmcnt(0)" ::: "memory");
      __builtin_amdgcn_sched_barrier(0);
      #define STC(ii, vv) { const int f = (ii) * 512 + tid; const int row = f >> 7; \
        const int k0 = (f & 127) * 8; \
        *(int4*)(sh + SH_ADDR(k0 >> 5, (row << 2) | ((k0 >> 3) & 3))) = vv; }
      STC(0, v0) STC(1, v1) STC(2, v2) STC(3, v3)
      #undef STC
    }
    __syncthreads();

    // ---- B: gates = xu(t) + h @ V  (conflict-free ds_reads) ----
    f32x4 acc = xacc;
    #pragma unroll
    for (int j = 0; j < 16; ++j) {
      const int u = ks * 16 + j;
      const bf16x8 af = *(const bf16x8*)(sh + SH_ADDR(u, slot_r));
      const bf16x8 bf = *(const bf16x8*)(sw + ((ct2 * 16 + j) * 64 + l) * 8);
      acc = __builtin_amdgcn_mfma_f32_16x16x32_bf16(af, bf, acc, 0, 0, 0);
    }
    __syncthreads();   // sh reads done -> overlay safe

    // ---- C: cross-(ct,ks) exchange via gl ----
    #pragma unroll
    for (int i = 0; i < 4; ++i)
      gl[(l16 * 4 + i) * 138 + ks * 68 + gcl] = acc[i];
    __syncthreads();

    // ---- D: combine + publish h + out stores, then drain & flag ----
    float hval = 0.0f;
    if (tid < 256) {
      const float* gr = gl + crow * 138;
      const float gi = gr[ 0 + ccj] + gr[68 +  0 + ccj];
      const float gf = gr[16 + ccj] + gr[68 + 16 + ccj];
      const float gg = gr[32 + ccj] + gr[68 + 32 + ccj];
      const float go = gr[48 + ccj] + gr[68 + 48 + ccj];
      const float i_ = sigm(gi), f_ = sigm(gf), g_ = sigm(gg), o_ = sigm(go);
      c_state = f_ * c_state + i_ * g_;
      hval = o_ * tanhf(c_state);
      if (t + 1 < T_) {
        const unsigned hv = (unsigned)f2bf(hval);
        short* hdst = hb + (size_t)((t + 1) & 1) * (B_ * H_)
                      + (size_t)(b0 + crow) * H_ + base + ccj;
        asm volatile("global_store_short %0, %1, off sc0 sc1" :: "v"(hdst), "v"(hv) : "memory");
      }
      // out stores issued here so their acks overlap the h-store drain
      out[((size_t)(b0 + crow) << 19) + (size_t)t * H_ + base + ccj] = hval;
      if (t == T_ - 1) {
        out[(size_t)B_ * T_ * H_ + (size_t)(b0 + crow) * H_ + base + ccj] = hval;
        out[(size_t)B_ * T_ * H_ + (size_t)B_ * H_ + (size_t)(b0 + crow) * H_ + base + ccj] = c_state;
      }
    }
    asm volatile("s_waitcnt vmcnt(0)" ::: "memory");   // per-wave drain (h + out)
    __syncthreads();                                    // all waves drained; gl reads done
    if (t + 1 < T_) {
      if (tid == 0) {
        const unsigned fv = (unsigned)(t + 1);
        asm volatile("global_store_dword %0, %1, off sc0 sc1" :: "v"(myflag), "v"(fv) : "memory");
      }

      // ---- E: write prefetched x(t+1) frags, prefetch x(t+2) ----
      *(int4*)(sh + xr0_addr) = xr0;
      *(int4*)(sh + xr1_addr) = xr1;
      {
        const size_t tn = (size_t)((t + 2 < T_) ? t + 2 : T_ - 1);
        xr0 = *(const int4*)(xsrc0 + tn * I_);
        xr1 = *(const int4*)(xsrc1 + tn * I_);
      }
      __syncthreads();

      // ---- F: xu(t+1) = bias + x(t+1) @ U ----
      xacc = (f32x4){bv_, bv_, bv_, bv_};
      #pragma unroll
      for (int j = 0; j < 8; ++j) {
        const int u = ks * 8 + j;
        const bf16x8 af = *(const bf16x8*)(sh + SH_ADDR(u, slot_r));
        xacc = __builtin_amdgcn_mfma_f32_16x16x32_bf16(af, ufr[j], xacc, 0, 0, 0);
      }
      __syncthreads();   // all waves done with sh before any wave's A(t+1) writes

      // ---- G: all waves poll; each proceeds to A as soon as flags are seen ----
      {
        unsigned v;
        for (;;) {
          asm volatile("global_load_dword %0, %1, off sc0 sc1" : "=v"(v) : "v"(pollp) : "memory");
          asm volatile("s_waitcnt vmcnt(0)" ::: "memory");
          if (__all((int)v > t)) break;
          asm volatile("s_sleep 1" ::: "memory");
        }
      }
    }
  }
}

extern "C" void kernel_launch(void* const* d_in, const int* in_sizes, int n_in,
                              void* d_out, int out_size, void* d_ws, size_t ws_size,
                              hipStream_t stream)
{
  const float* x  = (const float*)d_in[0];
  const float* U0 = (const float*)d_in[1];
  const float* Vg0 = (const float*)d_in[2];
  const float* bg0 = (const float*)d_in[3];
  const float* U1 = (const float*)d_in[4];
  const float* Vg1 = (const float*)d_in[5];
  const float* bg1 = (const float*)d_in[6];
  const float* U2 = (const float*)d_in[7];
  const float* Vg2 = (const float*)d_in[8];
  const float* bg2 = (const float*)d_in[9];
  const float* U3 = (const float*)d_in[10];
  const float* Vg3 = (const float*)d_in[11];
  const float* bg3 = (const float*)d_in[12];

  if (ws_size < WS_NEED) return;  // diagnostic: leaves d_out poisoned

  char* ws = (char*)d_ws;
  short* Wt = (short*)(ws + OFF_WT);
  short* xb = (short*)(ws + OFF_XB);
  short* hb = (short*)(ws + OFF_HB);
  unsigned* flg = (unsigned*)(ws + OFF_FLG);

  (void)hipFuncSetAttribute((const void*)lstm_rec,
                      hipFuncAttributeMaxDynamicSharedMemorySize, LDS_BYTES);

  (void)hipMemsetAsync(ws + OFF_HB, 0, (size_t)262144 + 16384, stream);
  pack_w_kernel<<<dim3(64, 24), 256, 0, stream>>>(U0, U1, U2, U3, Vg0, Vg1, Vg2, Vg3, Wt);
  xcvt<<<dim3(2048), 256, 0, stream>>>(x, xb);
  lstm_rec<<<dim3(GROUPS * GBLK), 512, LDS_BYTES, stream>>>(
      Wt, xb, bg0, bg1, bg2, bg3, hb, flg, (float*)d_out);
}

// Round 7
// 1143.119 us; speedup vs baseline: 5.7612x; 1.5140x over previous
//
#include <hip/hip_runtime.h>
#include <stdint.h>

#define B_  64
#define T_  512
#define I_  512
#define H_  1024
#define G4  4096
#define KW  1536   // rows of W_t = I_ + H_

#define GROUPS 4
#define GBLK   64    // col-blocks per group
#define MBR    16    // batch rows per group

#define LDS_BYTES 66048

typedef __attribute__((ext_vector_type(8))) short bf16x8;
typedef __attribute__((ext_vector_type(4))) float f32x4;

// ---- ws layout (bytes) ----
#define OFF_WT   ((size_t)0)                        // 4096*1536*2 = 12,582,912
#define OFF_XB   ((size_t)(16u << 20))              // x bf16: 64*512*512*2 = 33,554,432
#define OFF_HB   (OFF_XB + (size_t)33554432)        // tagged h: 2 par * 4 grp * 16 * 1024 * 2B = 262,144
#define WS_NEED  (OFF_HB + (size_t)262144)

__device__ __forceinline__ unsigned short f2bf(float x) {
  unsigned u = __float_as_uint(x);
  u += 0x7FFFu + ((u >> 16) & 1u);        // RNE
  return (unsigned short)(u >> 16);
}
__device__ __forceinline__ float sigm(float x) {
  return 1.0f / (1.0f + __expf(-x));
}

// ============ kernel 0: pack [U;V] -> W_t[col][k] bf16 (transposed) ============
__global__ __launch_bounds__(256) void pack_w_kernel(
    const float* __restrict__ U0, const float* __restrict__ U1,
    const float* __restrict__ U2, const float* __restrict__ U3,
    const float* __restrict__ V0, const float* __restrict__ V1,
    const float* __restrict__ V2, const float* __restrict__ V3,
    short* __restrict__ Wt)
{
  __shared__ short sl[64][65];
  const int c0 = blockIdx.x * 64;
  const int k0 = blockIdx.y * 64;
  const int g  = c0 >> 10;
  const int h0 = c0 & 1023;
  const float* srcU = (g == 0 ? U0 : g == 1 ? U1 : g == 2 ? U2 : U3);
  const float* srcV = (g == 0 ? V0 : g == 1 ? V1 : g == 2 ? V2 : V3);
  const float* src  = (k0 < 512) ? (srcU + (size_t)k0 * H_)
                                 : (srcV + (size_t)(k0 - 512) * H_);
  const int tid = threadIdx.x;
  const int cl = tid & 63;
  const int r4 = tid >> 6;
  #pragma unroll
  for (int r = 0; r < 16; ++r) {
    const int kl = r * 4 + r4;
    sl[kl][cl] = (short)f2bf(src[(size_t)kl * H_ + h0 + cl]);
  }
  __syncthreads();
  #pragma unroll
  for (int r = 0; r < 16; ++r) {
    const int cl2 = r * 4 + r4;
    Wt[(size_t)(c0 + cl2) * KW + k0 + cl] = sl[cl][cl2];
  }
}

// ============ kernel 1: x fp32 -> bf16 ============
__global__ __launch_bounds__(256) void xcvt(
    const float* __restrict__ x, short* __restrict__ xb)
{
  const int nt = 524288;
  const int idx = blockIdx.x * 256 + threadIdx.x;
  #pragma unroll
  for (int i = 0; i < 8; ++i) {
    const int j = idx + i * nt;
    const float4 v = ((const float4*)x)[j];
    uint2 pk;
    pk.x = (unsigned)f2bf(v.x) | ((unsigned)f2bf(v.y) << 16);
    pk.y = (unsigned)f2bf(v.z) | ((unsigned)f2bf(v.w) << 16);
    ((uint2*)xb)[j] = pk;
  }
}

// fragment address (shorts): slot XOR-swizzled within unit
#define FR_ADDR(unit, slot) ((((unit) * 64) + ((slot) ^ ((unit) & 7))) * 8)

// ============ kernel 2: persistent recurrence; V in regs; tag-in-data sync ============
__global__ __launch_bounds__(512, 2) void lstm_rec(
    const short* __restrict__ Wt, const short* __restrict__ xb,
    const float* __restrict__ b0g, const float* __restrict__ b1g,
    const float* __restrict__ b2g, const float* __restrict__ b3g,
    short* __restrict__ hb, float* __restrict__ out)
{
  extern __shared__ char smem[];
  short* sh = (short*)smem;                 // 32 KiB h frags (32 units x 64 slots x 16B)
  short* sx = (short*)(smem + 32768);       // 16 KiB x frags (16 units)
  float* gl = (float*)(smem + 49152);       // [16 rows][260] f32 partial-gate exchange

  const int tid = threadIdx.x;
  const int blk = blockIdx.x;
  const int g   = blk >> 6;                 // group (16 batch rows)
  const int bi  = blk & 63;
  const int base = bi * 16;                 // 16 h-cols per block per gate
  const int b0  = g * MBR;

  const int w = tid >> 6, l = tid & 63;
  const int kq = w & 3;                     // K quarter (256 of V-K, 128 of x-K)
  const int np = w >> 2;                    // col half: gates {2np, 2np+1}
  const int cit = l & 15;
  const int l16 = l >> 4;
  const int slot_r = (cit << 2) | l16;

  // ---- one-time: V fragments -> 64 VGPRs, U fragments -> 32 VGPRs ----
  bf16x8 vfr[2][8];
  bf16x8 ufr[2][4];
  #pragma unroll
  for (int n = 0; n < 2; ++n) {
    const int col = (np * 2 + n) * 1024 + base + cit;
    const short* wp = Wt + (size_t)col * KW;
    #pragma unroll
    for (int j = 0; j < 8; ++j)
      vfr[n][j] = *(const bf16x8*)(wp + 512 + kq * 256 + j * 32 + l16 * 8);
    #pragma unroll
    for (int j = 0; j < 4; ++j)
      ufr[n][j] = *(const bf16x8*)(wp + kq * 128 + j * 32 + l16 * 8);
  }

  const float* bias0 = (np == 0) ? b0g : b2g;
  const float* bias1 = (np == 0) ? b1g : b3g;
  const float bv0 = (kq == 0) ? bias0[base + cit] : 0.0f;
  const float bv1 = (kq == 0) ? bias1[base + cit] : 0.0f;

  const int crow = tid >> 4;                // combine row (tid<256)
  const int ccj  = tid & 15;

  // x-staging geometry (two 16B fragments per thread)
  const int xr0_row = tid >> 6;
  const int xr1_row = 8 + (tid >> 6);
  const int x_k0 = (tid & 63) * 8;
  const int x_unit = x_k0 >> 5;
  const int xr0_addr = FR_ADDR(x_unit, (xr0_row << 2) | (tid & 3));
  const int xr1_addr = FR_ADDR(x_unit, (xr1_row << 2) | (tid & 3));
  const short* xsrc0 = xb + (size_t)(b0 + xr0_row) * T_ * I_ + x_k0;
  const short* xsrc1 = xb + (size_t)(b0 + xr1_row) * T_ * I_ + x_k0;

  float c_state = 0.0f;

  // ---- prologue: stage x(0), xu(0), prefetch x(1) ----
  *(int4*)(sx + xr0_addr) = *(const int4*)(xsrc0);
  *(int4*)(sx + xr1_addr) = *(const int4*)(xsrc1);
  __syncthreads();
  f32x4 xacc0 = (f32x4){bv0, bv0, bv0, bv0};
  f32x4 xacc1 = (f32x4){bv1, bv1, bv1, bv1};
  #pragma unroll
  for (int j = 0; j < 4; ++j) {
    const bf16x8 xf = *(const bf16x8*)(sx + FR_ADDR(kq * 4 + j, slot_r));
    xacc0 = __builtin_amdgcn_mfma_f32_16x16x32_bf16(xf, ufr[0][j], xacc0, 0, 0, 0);
    xacc1 = __builtin_amdgcn_mfma_f32_16x16x32_bf16(xf, ufr[1][j], xacc1, 0, 0, 0);
  }
  int4 xr0 = *(const int4*)(xsrc0 + (size_t)1 * I_);
  int4 xr1 = *(const int4*)(xsrc1 + (size_t)1 * I_);

  for (int t = 0; t < T_; ++t) {
    { // ---- A: retry-load h(t) until step-tag bits match, then stage to sh ----
      const unsigned expw = ((t >> 1) & 1) ? 0x00010001u : 0u;
      const short* hsrc = hb + ((size_t)(t & 1) * GROUPS + g) * (MBR * H_);
      int4 v0, v1, v2, v3;
      for (;;) {
        #define LDC(ii, vv) { \
          const short* p = hsrc + (size_t)((((ii) * 512 + tid) >> 7)) * H_ \
                           + ((((ii) * 512 + tid) & 127) * 8); \
          asm volatile("global_load_dwordx4 %0, %1, off sc0 sc1" : "=&v"(vv) : "v"(p)); }
        LDC(0, v0) LDC(1, v1) LDC(2, v2) LDC(3, v3)
        #undef LDC
        asm volatile("s_waitcnt vmcnt(0)" ::: "memory");
        __builtin_amdgcn_sched_barrier(0);
        #define XR(vv) (((unsigned)(vv).x ^ expw) | ((unsigned)(vv).y ^ expw) | \
                        ((unsigned)(vv).z ^ expw) | ((unsigned)(vv).w ^ expw))
        const unsigned diff = (XR(v0) | XR(v1) | XR(v2) | XR(v3)) & 0x00010001u;
        #undef XR
        if (__all(diff == 0u)) break;
        asm volatile("s_sleep 1" ::: "memory");
      }
      #define STC(ii, vv) { const int f = (ii) * 512 + tid; const int row = f >> 7; \
        const int k0s = (f & 127) * 8; \
        *(int4*)(sh + FR_ADDR(k0s >> 5, (row << 2) | ((k0s >> 3) & 3))) = vv; }
      STC(0, v0) STC(1, v1) STC(2, v2) STC(3, v3)
      #undef STC
    }
    __syncthreads();                                   // barrier 1

    // ---- B: partial gates = xu_part + h @ V_part (V from registers) ----
    f32x4 acc0 = xacc0, acc1 = xacc1;
    #pragma unroll
    for (int j = 0; j < 8; ++j) {
      const bf16x8 af = *(const bf16x8*)(sh + FR_ADDR(kq * 8 + j, slot_r));
      acc0 = __builtin_amdgcn_mfma_f32_16x16x32_bf16(af, vfr[0][j], acc0, 0, 0, 0);
      acc1 = __builtin_amdgcn_mfma_f32_16x16x32_bf16(af, vfr[1][j], acc1, 0, 0, 0);
    }

    // ---- C: 4-way partial exchange ----
    #pragma unroll
    for (int i = 0; i < 4; ++i) {
      gl[(l16 * 4 + i) * 260 + kq * 64 + (np * 2 + 0) * 16 + cit] = acc0[i];
      gl[(l16 * 4 + i) * 260 + kq * 64 + (np * 2 + 1) * 16 + cit] = acc1[i];
    }
    __syncthreads();                                   // barrier 2

    // ---- D: combine; fire-and-forget tagged h stores; out stores ----
    if (tid < 256) {
      const float* gr = gl + crow * 260;
      float s[4];
      #pragma unroll
      for (int gate = 0; gate < 4; ++gate)
        s[gate] = gr[0 * 64 + gate * 16 + ccj] + gr[1 * 64 + gate * 16 + ccj]
                + gr[2 * 64 + gate * 16 + ccj] + gr[3 * 64 + gate * 16 + ccj];
      const float i_ = sigm(s[0]), f_ = sigm(s[1]), g_ = sigm(s[2]), o_ = sigm(s[3]);
      c_state = f_ * c_state + i_ * g_;
      const float hval = o_ * tanhf(c_state);
      if (t + 1 < T_) {
        unsigned hv = (unsigned)f2bf(hval);
        hv = (hv & ~1u) | (unsigned)(((t + 1) >> 1) & 1);   // steal LSB as step tag
        short* hdst = hb + ((size_t)((t + 1) & 1) * GROUPS + g) * (MBR * H_)
                      + (size_t)crow * H_ + base + ccj;
        asm volatile("global_store_short %0, %1, off sc0 sc1" :: "v"(hdst), "v"(hv) : "memory");
      }
      out[((size_t)(b0 + crow) << 19) + (size_t)t * H_ + base + ccj] = hval;
      if (t == T_ - 1) {
        out[(size_t)B_ * T_ * H_ + (size_t)(b0 + crow) * H_ + base + ccj] = hval;
        out[(size_t)B_ * T_ * H_ + (size_t)B_ * H_ + (size_t)(b0 + crow) * H_ + base + ccj] = c_state;
      }
    }

    if (t + 1 < T_) {
      // ---- E: write prefetched x(t+1), prefetch x(t+2) ----
      *(int4*)(sx + xr0_addr) = xr0;
      *(int4*)(sx + xr1_addr) = xr1;
      {
        const size_t tn = (size_t)((t + 2 < T_) ? t + 2 : T_ - 1);
        xr0 = *(const int4*)(xsrc0 + tn * I_);
        xr1 = *(const int4*)(xsrc1 + tn * I_);
      }
      __syncthreads();                                 // barrier 3

      // ---- F: xu(t+1) partial = bias + x(t+1) @ U_part ----
      xacc0 = (f32x4){bv0, bv0, bv0, bv0};
      xacc1 = (f32x4){bv1, bv1, bv1, bv1};
      #pragma unroll
      for (int j = 0; j < 4; ++j) {
        const bf16x8 xf = *(const bf16x8*)(sx + FR_ADDR(kq * 4 + j, slot_r));
        xacc0 = __builtin_amdgcn_mfma_f32_16x16x32_bf16(xf, ufr[0][j], xacc0, 0, 0, 0);
        xacc1 = __builtin_amdgcn_mfma_f32_16x16x32_bf16(xf, ufr[1][j], xacc1, 0, 0, 0);
      }
    }
  }
}

extern "C" void kernel_launch(void* const* d_in, const int* in_sizes, int n_in,
                              void* d_out, int out_size, void* d_ws, size_t ws_size,
                              hipStream_t stream)
{
  const float* x  = (const float*)d_in[0];
  const float* U0 = (const float*)d_in[1];
  const float* Vg0 = (const float*)d_in[2];
  const float* bg0 = (const float*)d_in[3];
  const float* U1 = (const float*)d_in[4];
  const float* Vg1 = (const float*)d_in[5];
  const float* bg1 = (const float*)d_in[6];
  const float* U2 = (const float*)d_in[7];
  const float* Vg2 = (const float*)d_in[8];
  const float* bg2 = (const float*)d_in[9];
  const float* U3 = (const float*)d_in[10];
  const float* Vg3 = (const float*)d_in[11];
  const float* bg3 = (const float*)d_in[12];

  if (ws_size < WS_NEED) return;  // diagnostic: leaves d_out poisoned

  char* ws = (char*)d_ws;
  short* Wt = (short*)(ws + OFF_WT);
  short* xb = (short*)(ws + OFF_XB);
  short* hb = (short*)(ws + OFF_HB);

  (void)hipFuncSetAttribute((const void*)lstm_rec,
                      hipFuncAttributeMaxDynamicSharedMemorySize, LDS_BYTES);

  // par 0: zeros -> valid h(0)=0 with tag bit 0. par 1: 0x0101 -> stale (bit 1) until h(1) lands.
  (void)hipMemsetAsync(ws + OFF_HB, 0x00, 131072, stream);
  (void)hipMemsetAsync(ws + OFF_HB + 131072, 0x01, 131072, stream);
  pack_w_kernel<<<dim3(64, 24), 256, 0, stream>>>(U0, U1, U2, U3, Vg0, Vg1, Vg2, Vg3, Wt);
  xcvt<<<dim3(2048), 256, 0, stream>>>(x, xb);
  lstm_rec<<<dim3(GROUPS * GBLK), 512, LDS_BYTES, stream>>>(
      Wt, xb, bg0, bg1, bg2, bg3, hb, (float*)d_out);
}